// Round 2
// 120.294 us; speedup vs baseline: 1.0304x; 1.0304x over previous
//
#include <hip/hip_runtime.h>

#define H 1024
#define SEQ 4096

typedef float f32x4 __attribute__((ext_vector_type(4)));
typedef short s16x8 __attribute__((ext_vector_type(8)));
typedef unsigned short u16;
typedef u16 u16x4 __attribute__((ext_vector_type(4)));
typedef u16 u16x8 __attribute__((ext_vector_type(8)));

__device__ inline u16 f2bf(float f) {
  union { float f; unsigned u; } v; v.f = f;
  unsigned r = v.u + 0x7fffu + ((v.u >> 16) & 1u);
  return (u16)(r >> 16);
}
__device__ inline float bf2f(u16 b) {
  union { unsigned u; float f; } v; v.u = ((unsigned)b) << 16; return v.f;
}

__device__ __forceinline__ void cvt16(const float* __restrict__ src, u16* __restrict__ dst, int i) {
  const float4* s = reinterpret_cast<const float4*>(src) + (size_t)i * 4;
  float4 a = s[0], b = s[1], c = s[2], d = s[3];
  u16x8 lo, hi;
  lo[0]=f2bf(a.x); lo[1]=f2bf(a.y); lo[2]=f2bf(a.z); lo[3]=f2bf(a.w);
  lo[4]=f2bf(b.x); lo[5]=f2bf(b.y); lo[6]=f2bf(b.z); lo[7]=f2bf(b.w);
  hi[0]=f2bf(c.x); hi[1]=f2bf(c.y); hi[2]=f2bf(c.z); hi[3]=f2bf(c.w);
  hi[4]=f2bf(d.x); hi[5]=f2bf(d.y); hi[6]=f2bf(d.z); hi[7]=f2bf(d.w);
  u16x8* o = reinterpret_cast<u16x8*>(dst) + (size_t)i * 2;
  o[0] = lo; o[1] = hi;
}

// =============== prep: Wq transpose, Wk/Wv/x cvt, wgs/zeros ===============
__global__ __launch_bounds__(256) void prep_kernel(
    const float* __restrict__ Wq, const float* __restrict__ Wk,
    const float* __restrict__ Wv, const float* __restrict__ x,
    const float* __restrict__ Wg,
    u16* __restrict__ wqTb, u16* __restrict__ wkb, u16* __restrict__ wvb,
    u16* __restrict__ xb, float* __restrict__ wgs, float* __restrict__ zeros) {
  __shared__ u16 tls[64][65];
  int blk = blockIdx.x, t = threadIdx.x;
  if (blk < 256) {
    int ti = blk >> 4, tj = blk & 15;
    int lr = t >> 2, cq = (t & 3) * 16;
    const float* s = Wq + (size_t)(ti * 64 + lr) * H + tj * 64 + cq;
#pragma unroll
    for (int q = 0; q < 4; ++q) {
      float4 v = *reinterpret_cast<const float4*>(s + q * 4);
      tls[lr][cq + q * 4 + 0] = f2bf(v.x);
      tls[lr][cq + q * 4 + 1] = f2bf(v.y);
      tls[lr][cq + q * 4 + 2] = f2bf(v.z);
      tls[lr][cq + q * 4 + 3] = f2bf(v.w);
    }
    __syncthreads();
    u16x8 a, b2;
#pragma unroll
    for (int i = 0; i < 8; ++i) a[i] = tls[cq + i][lr];
#pragma unroll
    for (int i = 0; i < 8; ++i) b2[i] = tls[cq + 8 + i][lr];
    u16* d = wqTb + (size_t)(tj * 64 + lr) * H + ti * 64 + cq;
    *reinterpret_cast<u16x8*>(d) = a;
    *reinterpret_cast<u16x8*>(d + 8) = b2;
  } else if (blk < 512) {
    cvt16(Wk, wkb, (blk - 256) * 256 + t);
  } else if (blk < 768) {
    cvt16(Wv, wvb, (blk - 512) * 256 + t);
  } else if (blk < 896) {
    cvt16(x, xb, (blk - 768) * 256 + t);
  } else {
    int i = t * 4;
    float4 a = *reinterpret_cast<const float4*>(Wg + i);
    float4 b2 = *reinterpret_cast<const float4*>(Wg + H + i);
    float4 o; o.x=a.x+b2.x; o.y=a.y+b2.y; o.z=a.z+b2.z; o.w=a.w+b2.w;
    *reinterpret_cast<float4*>(wgs + i) = o;
    float4 z; z.x=0.f; z.y=0.f; z.z=0.f; z.w=0.f;
    *reinterpret_cast<float4*>(zeros + i) = z;
  }
}

// ---- shared GEMM body: out = A(bf16 MxK) * W^T(bf16 NxK) + bias ----
__device__ __forceinline__ void gemm_body(const u16* __restrict__ A, const u16* __restrict__ W,
                                          const float* __restrict__ bias, u16* __restrict__ out,
                                          int mt, int nt, int omode, u16* sm) {
  int m0 = mt * 128, n0 = nt * 128;
  int t = threadIdx.x;
  int wave = t >> 6, lane = t & 63;
  int lane15 = lane & 15, lhi = lane >> 4;
  int wr = wave >> 1, wc = wave & 1;
  u16* a_sm = sm;
  u16* b_sm = sm + 8192;

  f32x4 acc[4][4];
#pragma unroll
  for (int mi = 0; mi < 4; ++mi)
#pragma unroll
    for (int ni = 0; ni < 4; ++ni) acc[mi][ni] = (f32x4)0.f;

  int rsel = wave * 32 + (lane >> 3);
  int csel = (lane & 7) * 8;
  const u16* Ab = A + (size_t)m0 * H + csel;
  const u16* Wb = W + (size_t)n0 * H + csel;

  for (int kt = 0; kt < 16; ++kt) {
    int kc = kt * 64;
#pragma unroll
    for (int j = 0; j < 4; ++j) {
      const u16* ga = Ab + (size_t)(rsel + j * 8) * H + kc;
      const u16* gb = Wb + (size_t)(rsel + j * 8) * H + kc;
      __builtin_amdgcn_global_load_lds((const __attribute__((address_space(1))) unsigned int*)ga,
                                       (__attribute__((address_space(3))) unsigned int*)&a_sm[wave * 2048 + j * 512],
                                       16, 0, 0);
      __builtin_amdgcn_global_load_lds((const __attribute__((address_space(1))) unsigned int*)gb,
                                       (__attribute__((address_space(3))) unsigned int*)&b_sm[wave * 2048 + j * 512],
                                       16, 0, 0);
    }
    __syncthreads();
#pragma unroll
    for (int ks = 0; ks < 2; ++ks) {
      s16x8 af[4], bfr[4];
#pragma unroll
      for (int mi = 0; mi < 4; ++mi)
        af[mi] = *reinterpret_cast<const s16x8*>(&a_sm[(wr * 64 + mi * 16 + lane15) * 64 + ks * 32 + lhi * 8]);
#pragma unroll
      for (int ni = 0; ni < 4; ++ni)
        bfr[ni] = *reinterpret_cast<const s16x8*>(&b_sm[(wc * 64 + ni * 16 + lane15) * 64 + ks * 32 + lhi * 8]);
#pragma unroll
      for (int mi = 0; mi < 4; ++mi)
#pragma unroll
        for (int ni = 0; ni < 4; ++ni)
          acc[mi][ni] = __builtin_amdgcn_mfma_f32_16x16x32_bf16(af[mi], bfr[ni], acc[mi][ni], 0, 0, 0);
    }
    __syncthreads();
  }

  float bqv[4];
#pragma unroll
  for (int ni = 0; ni < 4; ++ni) bqv[ni] = bias[n0 + wc * 64 + ni * 16 + lane15];

  if (omode == 0) {
#pragma unroll
    for (int mi = 0; mi < 4; ++mi)
#pragma unroll
      for (int ni = 0; ni < 4; ++ni)
#pragma unroll
        for (int r = 0; r < 4; ++r)
          sm[(wr * 64 + mi * 16 + lhi * 4 + r) * 128 + wc * 64 + ni * 16 + lane15] =
              f2bf(acc[mi][ni][r] + bqv[ni]);
    __syncthreads();
#pragma unroll
    for (int i = 0; i < 4; ++i) {
      int lin2 = i * 4096 + t * 16;
      int row = lin2 >> 7, col = lin2 & 127;
      u16x8 v0 = *reinterpret_cast<const u16x8*>(&sm[lin2]);
      u16x8 v1 = *reinterpret_cast<const u16x8*>(&sm[lin2 + 8]);
      u16* o = out + (size_t)(m0 + row) * H + n0 + col;
      *reinterpret_cast<u16x8*>(o) = v0;
      *reinterpret_cast<u16x8*>(o + 8) = v1;
    }
  } else {
#pragma unroll
    for (int mi = 0; mi < 4; ++mi)
#pragma unroll
      for (int ni = 0; ni < 4; ++ni) {
        int col = n0 + wc * 64 + ni * 16 + lane15;
#pragma unroll
        for (int r = 0; r < 4; ++r) {
          int row = m0 + wr * 64 + mi * 16 + lhi * 4 + r;
          out[((size_t)(row >> 6) * H + col) * 64 + (row & 63)] = f2bf(acc[mi][ni][r] + bqv[ni]);
        }
      }
  }
}

// kv1: k = x.Wk^T + bk (row-major), vT = (x.Wv^T + bv)^T
__global__ __launch_bounds__(256) void kv1_kernel(const u16* __restrict__ xb,
                                                  const u16* __restrict__ wkb, const u16* __restrict__ wvb,
                                                  const float* __restrict__ bk, const float* __restrict__ bv,
                                                  u16* __restrict__ kbf, u16* __restrict__ vTb) {
  __shared__ __align__(16) u16 sm[128 * 128];
  int sel = blockIdx.x >> 5;
  int bid = blockIdx.x & 31;
  if (sel == 0)
    gemm_body(xb, wkb, bk, kbf, bid >> 3, bid & 7, 0, sm);
  else
    gemm_body(xb, wvb, bv, vTb, bid >> 3, bid & 7, 2, sm);
}

// kv2: blocks 0-31: ktilde = k.Wq; blocks 32-39: vg = vT.Wg0, bqk = k.bq
__global__ __launch_bounds__(256) void kv2_kernel(const u16* __restrict__ kbf,
                                                  const u16* __restrict__ wqTb,
                                                  const float* __restrict__ zeros,
                                                  u16* __restrict__ ktb,
                                                  const u16* __restrict__ vTb,
                                                  const float* __restrict__ Wg,
                                                  const float* __restrict__ bq,
                                                  float* __restrict__ vg, float* __restrict__ bqk) {
  if (blockIdx.x < 32) {
    __shared__ __align__(16) u16 sm[128 * 128];
    gemm_body(kbf, wqTb, zeros, ktb, blockIdx.x >> 3, blockIdx.x & 7, 0, sm);
  } else {
    __shared__ float bq_s[H];
    __shared__ float partial[4][64];
    int b = blockIdx.x - 32, t = threadIdx.x;
    *reinterpret_cast<float4*>(&bq_s[t * 4]) = *reinterpret_cast<const float4*>(bq + t * 4);
    int l = t & 63, part = t >> 6;
    float s = 0.f;
    const u16* vtp = vTb + ((size_t)b * H + part * 256) * 64 + l;
    for (int h = 0; h < 256; ++h) s += bf2f(vtp[h * 64]) * Wg[part * 256 + h];
    partial[part][l] = s;
    __syncthreads();
    if (t < 64) vg[b * 64 + t] = partial[0][t] + partial[1][t] + partial[2][t] + partial[3][t];
    int row = t >> 2, qp = t & 3;
    const u16* kr = kbf + ((size_t)b * 64 + row) * H + qp * 256;
    float sb = 0.f;
    for (int j = 0; j < 256; j += 8) {
      u16x8 v8 = *reinterpret_cast<const u16x8*>(kr + j);
      const float* bqp = &bq_s[qp * 256 + j];
#pragma unroll
      for (int i2 = 0; i2 < 8; ++i2) sb += bf2f(v8[i2]) * bqp[i2];
    }
    sb += __shfl_xor(sb, 1);
    sb += __shfl_xor(sb, 2);
    if (qp == 0) bqk[b * 64 + row] = sb;
  }
}

// =============== fused attention: QBLK=32, 4 waves (16 waves/CU), 3-deep k staging + 3-set p regs ===============
// Wave w: QK sub-tile rows [(w&1)*16,+16) x cols [(w>>1)*32,+32); PV H-slice [w*256,+256) (4 hcc x 64).
// Softmax: no max-subtraction (|s|max ~55 << fp32/bf16 exp range); raw e stored in P_lds;
// half-row sums combined via LDS; 1/(32*sum) folded into per-row gate scale gs_l.
__global__ __launch_bounds__(256, 4) void attn_kernel(
    const float* __restrict__ p, const u16* __restrict__ ktb,
    const u16* __restrict__ vT, const float* __restrict__ wgs,
    const float* __restrict__ vg, const float* __restrict__ bqk,
    const float* __restrict__ bg, float* __restrict__ out) {
  int t = threadIdx.x;
  int orig = blockIdx.x;
  int lin = (orig & 7) * 128 + (orig >> 3);  // batch-per-XCD locality (1024 = 8*128)
  int b = lin >> 7, st = lin & 127;
  size_t gm0 = (size_t)b * SEQ + (size_t)st * 32;
  int wave = t >> 6, lane = t & 63, lane15 = lane & 15, lhi = lane >> 4;
  int wr = wave & 1, wc2 = wave >> 1;

  __shared__ __align__(16) u16 smem_u[16384];  // 32 KB: kbuf[3][64*64] | pbuf[2][32*64]; PV: f32 scratch[4][32*64]
  __shared__ float wgs_l[H];                   // 4 KB
  __shared__ float sum_l[2][32], gv_l[2][32];
  __shared__ float gs_l[32], pg_l[32], vg_l[64], bq_l[64];

#define KBUF(bb) (&smem_u[(bb) * 4096])
#define PBUF(bb) (&smem_u[12288 + (bb) * 2048])

  *reinterpret_cast<float4*>(&wgs_l[t * 4]) = *reinterpret_cast<const float4*>(wgs + t * 4);
  if (t < 64) { vg_l[t] = vg[b * 64 + t]; bq_l[t] = bqk[b * 64 + t]; }

  const u16* kb = ktb + (size_t)b * 64 * H;
  int ar = t >> 3, aq = t & 7;               // p-stage: row 0..31, col-eighth (8 cols)
  int awz = (ar & 7) << 3;
  const float* prow = p + (gm0 + ar) * H + aq * 8;
  float pgs = 0.f;

#define KSTAGE(buf, kc)                                                                   \
  {                                                                                       \
    _Pragma("unroll")                                                                     \
    for (int j = 0; j < 2; ++j) {                                                         \
      int row_ = j * 32 + wave * 8 + (lane >> 3);                                         \
      int off_ = (kc) + (((lane & 7) * 8) ^ ((row_ & 7) << 3));                           \
      __builtin_amdgcn_global_load_lds(                                                   \
          (const __attribute__((address_space(1))) unsigned int*)(kb + (size_t)row_ * H + off_), \
          (__attribute__((address_space(3))) unsigned int*)(KBUF(buf) + j * 2048 + wave * 512),  \
          16, 0, 0);                                                                      \
    }                                                                                     \
  }

#define CVT_WRITE(buf, R, kc)                                                             \
  {                                                                                       \
    const float* w_ = &wgs_l[(kc) + aq * 8];                                              \
    pgs += R[0].x*w_[0]+R[0].y*w_[1]+R[0].z*w_[2]+R[0].w*w_[3]                            \
         + R[1].x*w_[4]+R[1].y*w_[5]+R[1].z*w_[6]+R[1].w*w_[7];                           \
    u16x8 o_;                                                                             \
    o_[0]=f2bf(R[0].x); o_[1]=f2bf(R[0].y); o_[2]=f2bf(R[0].z); o_[3]=f2bf(R[0].w);       \
    o_[4]=f2bf(R[1].x); o_[5]=f2bf(R[1].y); o_[6]=f2bf(R[1].z); o_[7]=f2bf(R[1].w);       \
    *reinterpret_cast<u16x8*>(&PBUF(buf)[ar * 64 + ((aq * 8) ^ awz)]) = o_;               \
  }

#define PLOAD(R, kc)                                                                      \
  {                                                                                       \
    const float* pr_ = prow + (kc);                                                       \
    R[0] = *reinterpret_cast<const float4*>(pr_);                                         \
    R[1] = *reinterpret_cast<const float4*>(pr_ + 4);                                     \
  }

  float4 rA[2], rB[2], rC[2];
  // prologue: k0,k1 staged; p chunks 0,1,2 loaded
  KSTAGE(0, 0);
  KSTAGE(1, 64);
  PLOAD(rA, 0);
  PLOAD(rB, 64);
  PLOAD(rC, 128);
  __syncthreads();          // wgs_l/vg/bq visible; k0,k1 staged (full drain, once)
  CVT_WRITE(0, rA, 0);
  PLOAD(rA, 192);
  // chunk-0 pbuf rows are cross-wave (writer rows w*8.. vs reader rows (w&1)*16..): barrier needed
  asm volatile("s_waitcnt lgkmcnt(0)" ::: "memory");
  __builtin_amdgcn_s_barrier();
  asm volatile("" ::: "memory");

  f32x4 sacc[2];
  sacc[0] = (f32x4)0.f;
  sacc[1] = (f32x4)0.f;
  int aswz = (lane15 & 7) << 3;

  for (int kt = 0; kt < 16; ++kt) {
    int cur3 = kt % 3, cur2 = kt & 1;
    if (kt < 14) KSTAGE((kt + 2) % 3, (kt + 2) * 64);
    __builtin_amdgcn_sched_barrier(0);
    if (kt < 15) {
      // consume the set holding chunk kt+1 (= set (kt+1)%3), refill with chunk kt+4
      int sel = (kt + 1) % 3;
      if (sel == 0)      { CVT_WRITE(cur2 ^ 1, rA, (kt + 1) * 64); if (kt < 12) PLOAD(rA, (kt + 4) * 64); }
      else if (sel == 1) { CVT_WRITE(cur2 ^ 1, rB, (kt + 1) * 64); if (kt < 12) PLOAD(rB, (kt + 4) * 64); }
      else               { CVT_WRITE(cur2 ^ 1, rC, (kt + 1) * 64); if (kt < 12) PLOAD(rC, (kt + 4) * 64); }
    }
#pragma unroll
    for (int ks2 = 0; ks2 < 2; ++ks2) {
      int col = ks2 * 32 + lhi * 8;
      s16x8 ap = *reinterpret_cast<const s16x8*>(&PBUF(cur2)[(wr * 16 + lane15) * 64 + (col ^ aswz)]);
#pragma unroll
      for (int ni = 0; ni < 2; ++ni) {
        int brow = wc2 * 32 + ni * 16 + lane15;
        s16x8 bk8 = *reinterpret_cast<const s16x8*>(&KBUF(cur3)[brow * 64 + (col ^ ((brow & 7) << 3))]);
        sacc[ni] = __builtin_amdgcn_mfma_f32_16x16x32_bf16(ap, bk8, sacc[ni], 0, 0, 0);
      }
    }
    // counted waits (FIFO-derived, 4 issues/iter steady): keep prev-iter PLOAD(2) + this iter(4) = 6;
    // tail: kt=12 keep 4 (K14+P15), kt=13 keep 2 (K15), then drain. lgkmcnt(0): cross-wave pbuf writes.
    if (kt <= 11) {
      asm volatile("s_waitcnt vmcnt(6) lgkmcnt(0)" ::: "memory");
    } else if (kt == 12) {
      asm volatile("s_waitcnt vmcnt(4) lgkmcnt(0)" ::: "memory");
    } else if (kt == 13) {
      asm volatile("s_waitcnt vmcnt(2) lgkmcnt(0)" ::: "memory");
    } else {
      asm volatile("s_waitcnt vmcnt(0) lgkmcnt(0)" ::: "memory");
    }
    __builtin_amdgcn_s_barrier();
    asm volatile("" ::: "memory");
  }

  // pg reduce (8 threads per row share the row's partial sums)
  pgs += __shfl_xor(pgs, 1);
  pgs += __shfl_xor(pgs, 2);
  pgs += __shfl_xor(pgs, 4);
  if (aq == 0) pg_l[ar] = pgs;

  // ---- softmax partials (no max-sub): raw e -> P_lds; half-row sum + gate dot -> LDS ----
  u16* P_lds = PBUF(0);  // [32][72] aliased (2304 u16 <= 4096)
  {
    float vgl[2], bql[2];
#pragma unroll
    for (int ni = 0; ni < 2; ++ni) {
      int c = wc2 * 32 + ni * 16 + lane15;
      vgl[ni] = vg_l[c];
      bql[ni] = bq_l[c];
    }
#pragma unroll
    for (int r = 0; r < 4; ++r) {
      int row = wr * 16 + lhi * 4 + r;
      float e0 = __expf(sacc[0][r] + bql[0]);
      float e1 = __expf(sacc[1][r] + bql[1]);
      float se = e0 + e1;
      float sv = e0 * vgl[0] + e1 * vgl[1];
      se += __shfl_xor(se, 1); se += __shfl_xor(se, 2);
      se += __shfl_xor(se, 4); se += __shfl_xor(se, 8);
      sv += __shfl_xor(sv, 1); sv += __shfl_xor(sv, 2);
      sv += __shfl_xor(sv, 4); sv += __shfl_xor(sv, 8);
      P_lds[row * 72 + wc2 * 32 + lane15] = f2bf(e0);
      P_lds[row * 72 + wc2 * 32 + 16 + lane15] = f2bf(e1);
      if (lane15 == 0) { sum_l[wc2][row] = se; gv_l[wc2][row] = sv; }
    }
  }
  __syncthreads();

  // combine halves: per-row scale gs = sigmoid(logit) / (32*sum)
  if (t < 32) {
    float ssum = sum_l[0][t] + sum_l[1][t];
    float inv = 1.f / (32.f * ssum);
    float logit = (gv_l[0][t] + gv_l[1][t]) * inv + pg_l[t] + bg[0];
    gs_l[t] = inv / (1.f + __expf(-logit));
  }

  // P fragments to regs before scratch (wave 3's scratch aliases P_lds)
  s16x8 pa[2][2];
#pragma unroll
  for (int mi = 0; mi < 2; ++mi)
#pragma unroll
    for (int ks = 0; ks < 2; ++ks)
      pa[mi][ks] = *reinterpret_cast<const s16x8*>(&P_lds[(mi * 16 + lane15) * 72 + ks * 32 + lhi * 8]);
  asm volatile("s_waitcnt lgkmcnt(0)" ::: "memory");
  __syncthreads();

  // ---- PV + coalesced epilogue: out = p + gs*(raw PV) ; wave owns H-slice [wave*256,+256) ----
  {
    const u16* vb = vT + (size_t)b * H * 64;
    float* sc = reinterpret_cast<float*>(&smem_u[0]) + wave * 2048;  // [32][64] per wave
#pragma unroll
    for (int hcc = 0; hcc < 4; ++hcc) {
      int hbase = wave * 256 + hcc * 64;
      f32x4 acc[2][4];
#pragma unroll
      for (int mi = 0; mi < 2; ++mi)
#pragma unroll
        for (int ni = 0; ni < 4; ++ni) acc[mi][ni] = (f32x4)0.f;
#pragma unroll
      for (int ks = 0; ks < 2; ++ks) {
        s16x8 bv8[4];
#pragma unroll
        for (int ni = 0; ni < 4; ++ni)
          bv8[ni] = *reinterpret_cast<const s16x8*>(vb + (size_t)(hbase + ni * 16 + lane15) * 64 + ks * 32 + lhi * 8);
#pragma unroll
        for (int mi = 0; mi < 2; ++mi)
#pragma unroll
          for (int ni = 0; ni < 4; ++ni)
            acc[mi][ni] = __builtin_amdgcn_mfma_f32_16x16x32_bf16(pa[mi][ks], bv8[ni], acc[mi][ni], 0, 0, 0);
      }
      int swz = (lhi & 1) << 4;
#pragma unroll
      for (int mi = 0; mi < 2; ++mi)
#pragma unroll
        for (int ni = 0; ni < 4; ++ni)
#pragma unroll
          for (int r = 0; r < 4; ++r)
            sc[(mi * 16 + lhi * 4 + r) * 64 + ((ni * 16 + lane15) ^ swz)] = acc[mi][ni][r];
      asm volatile("s_waitcnt lgkmcnt(0)" ::: "memory");
      __builtin_amdgcn_sched_barrier(0);
#pragma unroll
      for (int ii = 0; ii < 8; ++ii) {
        int flat4 = ii * 64 + lane;
        int lrow = flat4 >> 4;
        int c4 = flat4 & 15;
        int scol = (c4 * 4) ^ (((lrow >> 2) & 1) << 4);
        f32x4 a = *reinterpret_cast<const f32x4*>(&sc[lrow * 64 + scol]);
        size_t grow = gm0 + lrow;
        float f = gs_l[lrow];
        float4 pr4 = *reinterpret_cast<const float4*>(&p[grow * H + hbase + c4 * 4]);
        f32x4 o;
        o[0] = pr4.x + f * a[0];
        o[1] = pr4.y + f * a[1];
        o[2] = pr4.z + f * a[2];
        o[3] = pr4.w + f * a[3];
        *reinterpret_cast<f32x4*>(&out[grow * H + hbase + c4 * 4]) = o;
      }
      asm volatile("s_waitcnt lgkmcnt(0)" ::: "memory");
    }
  }
#undef KSTAGE
#undef CVT_WRITE
#undef PLOAD
#undef KBUF
#undef PBUF
}

extern "C" void kernel_launch(void* const* d_in, const int* in_sizes, int n_in,
                              void* d_out, int out_size, void* d_ws, size_t ws_size,
                              hipStream_t stream) {
  const float* p  = (const float*)d_in[0];
  const float* x  = (const float*)d_in[1];
  const float* Wq = (const float*)d_in[2];
  const float* bq = (const float*)d_in[3];
  const float* Wk = (const float*)d_in[4];
  const float* bk = (const float*)d_in[5];
  const float* Wv = (const float*)d_in[6];
  const float* bv = (const float*)d_in[7];
  const float* Wg = (const float*)d_in[8];
  const float* bg = (const float*)d_in[9];
  float* out = (float*)d_out;

  char* ws = (char*)d_ws;
  u16* wqTb    = (u16*)(ws);                    // 2 MiB
  u16* wkb     = (u16*)(ws + 2097152);          // 2 MiB
  u16* wvb     = (u16*)(ws + 4194304);          // 2 MiB
  u16* xb      = (u16*)(ws + 6291456);          // 1 MiB
  u16* kbf     = (u16*)(ws + 7340032);          // 1 MiB
  u16* ktb     = (u16*)(ws + 8388608);          // 1 MiB
  u16* vTb     = (u16*)(ws + 9437184);          // 1 MiB
  float* wgs   = (float*)(ws + 10485760);
  float* zeros = (float*)(ws + 10489856);
  float* vg    = (float*)(ws + 10493952);
  float* bqk   = (float*)(ws + 10498048);

  prep_kernel<<<897, 256, 0, stream>>>(Wq, Wk, Wv, x, Wg, wqTb, wkb, wvb, xb, wgs, zeros);
  kv1_kernel<<<64, 256, 0, stream>>>(xb, wkb, wvb, bk, bv, kbf, vTb);
  kv2_kernel<<<40, 256, 0, stream>>>(kbf, wqTb, zeros, ktb, vTb, Wg, bq, vg, bqk);
  attn_kernel<<<1024, 256, 0, stream>>>(p, ktb, vTb, wgs, vg, bqk, bg, out);
}